// Round 1
// baseline (325.127 us; speedup 1.0000x reference)
//
#include <hip/hip_runtime.h>

#define CH   128
#define KS   7
#define R    49          // KS*KS
#define HH   56
#define NPOS 3136        // HH*HH
#define BS   8
#define XSTR 401408      // CH*NPOS (one batch plane of x)
#define XTOT (BS*XSTR)

__global__ __launch_bounds__(256) void poatt_kernel(
    const float* __restrict__ x,    // (8,128,56,56) flat
    const float* __restrict__ W1,   // (2,128)
    const float* __restrict__ b1,   // (128)
    const float* __restrict__ W2,   // (128,128)
    const float* __restrict__ b2,   // (128)
    float* __restrict__ out)        // (8,128,3136) flat
{
    __shared__ float rel_s[R][2];
    __shared__ float hid_s[R * CH];   // phase 1-2: hidden; phase 4: x window (6272 floats)
    __shared__ float P_s[R][CH];      // P, then softmaxed+masked weights
    __shared__ float part_s[CH];

    const int pos = blockIdx.x;
    const int tid = threadIdx.x;
    const int ch  = tid & (CH - 1);
    const int g   = tid >> 7;         // wave-uniform half-block id (0/1)

    const int q  = pos >> 6;          // = F / 401408, block-uniform
    const int ii = q / KS;
    const int jj = q % KS;

    // ---------- phase 0: rel[rr][e] for this pos (coords nbhd extract, d=2) ----------
    if (tid < 2 * R) {
        const int e  = (tid >= R) ? 1 : 0;
        const int rr = tid - e * R;
        int F  = (pos * 2 + e) * R + rr;
        int ep = F & 1;
        int t  = F >> 1;
        int jp = t % HH; t /= HH;
        int a  = t % HH; t /= HH;
        int jc = t % KS;
        int ic = t / KS;
        int row = jp + ic - 3;
        int col = ep + jc - 3;
        float v = 0.0f;
        if (row >= 0 && row < HH && (col == 0 || col == 1)) {
            int f    = a * (HH * 2) + row * 2 + col;
            int cidx = f / NPOS;
            int p    = f - cidx * NPOS;
            int u    = (cidx == 0) ? (p / HH) : (p % HH);
            v = -3.0f + 6.0f * (float)u * (1.0f / 55.0f);
        }
        const float c0 = -3.0f + 6.0f * (float)(pos / HH) * (1.0f / 55.0f);
        const float c1 = -3.0f + 6.0f * (float)(pos % HH) * (1.0f / 55.0f);
        rel_s[rr][e] = v - ((e == 0) ? c0 : c1);
    }
    __syncthreads();

    // ---------- phase 1: hidden = relu(rel @ W1 + b1) ----------
    {
        const float w10 = W1[ch];
        const float w11 = W1[CH + ch];
        const float bb  = b1[ch];
        for (int rr = g; rr < R; rr += 2) {
            float h = fmaf(rel_s[rr][0], w10, fmaf(rel_s[rr][1], w11, bb));
            hid_s[rr * CH + ch] = fmaxf(h, 0.0f);
        }
    }
    __syncthreads();

    // ---------- phase 2: P[rr][ch] = b2[ch] + sum_m hid[rr][m] * W2[m][ch] ----------
    {
        const int rr0 = g ? 25 : 0;
        const int nrr = g ? 24 : 25;
        float p[25];
        const float bb = b2[ch];
        #pragma unroll
        for (int i = 0; i < 25; ++i) p[i] = bb;
        for (int m4 = 0; m4 < CH / 4; ++m4) {
            float4 w;
            w.x = W2[(m4 * 4 + 0) * CH + ch];
            w.y = W2[(m4 * 4 + 1) * CH + ch];
            w.z = W2[(m4 * 4 + 2) * CH + ch];
            w.w = W2[(m4 * 4 + 3) * CH + ch];
            #pragma unroll
            for (int i = 0; i < 25; ++i) {
                if (i < nrr) {
                    const float4 h = *reinterpret_cast<const float4*>(&hid_s[(rr0 + i) * CH + m4 * 4]);
                    p[i] = fmaf(h.x, w.x, fmaf(h.y, w.y, fmaf(h.z, w.z, fmaf(h.w, w.w, p[i]))));
                }
            }
        }
        for (int i = 0; i < nrr; ++i) P_s[rr0 + i][ch] = p[i];
    }
    __syncthreads();

    // ---------- phase 3: softmax over rr per ch + fold V-validity mask into weights ----------
    if (g == 0) {
        float mx = -1e30f;
        for (int rr = 0; rr < R; ++rr) mx = fmaxf(mx, P_s[rr][ch]);
        float s = 0.0f;
        for (int rr = 0; rr < R; ++rr) {
            float e = __expf(P_s[rr][ch] - mx);
            s += e;
            P_s[rr][ch] = e;
        }
        const float inv = 1.0f / s;
        const int wb0 = (pos & 63) * (R * CH);
        for (int rr = 0; rr < R; ++rr) {
            int rem = wb0 + ch * R + rr;
            int e2  = rem & (CH - 1);
            int j2  = (rem >> 7) % HH;
            int row = j2 + ii - 3;
            int col = e2 + jj - 3;
            bool valid = (row >= 0) && (row < HH) && (col >= 0) && (col < CH);
            P_s[rr][ch] = valid ? P_s[rr][ch] * inv : 0.0f;
        }
    }
    __syncthreads();

    // ---------- phase 4: per-batch contiguous-window stage + weighted gather ----------
    float wreg[25];
    {
        const int rr0 = g * 25;
        #pragma unroll
        for (int i = 0; i < 25; ++i) {
            int rr = rr0 + i;
            wreg[i] = (rr < R) ? P_s[rr][ch] : 0.0f;
        }
    }
    const int lbase   = ch * R + g * 25;
    const int winbase = (pos & 63) * (R * CH) + (ii - 3) * CH + (jj - 3);

    for (int b = 0; b < BS; ++b) {
        // stage contiguous window of x[b] into LDS (coalesced; OOB -> 0, masked anyway)
        for (int t = tid; t < R * CH; t += 256) {
            int gg = b * XSTR + winbase + t;
            hid_s[t] = (gg >= 0 && gg < XTOT) ? x[gg] : 0.0f;
        }
        __syncthreads();

        float acc = 0.0f;
        #pragma unroll
        for (int i = 0; i < 25; ++i) {
            int li = lbase + i;
            if (li >= R * CH) li = 0;           // only the dead (weight=0) tail slot
            acc = fmaf(wreg[i], hid_s[li], acc);
        }
        if (g) part_s[ch] = acc;
        __syncthreads();
        if (!g) out[(size_t)(b * CH + ch) * NPOS + pos] = acc + part_s[ch];
    }
}

extern "C" void kernel_launch(void* const* d_in, const int* in_sizes, int n_in,
                              void* d_out, int out_size, void* d_ws, size_t ws_size,
                              hipStream_t stream) {
    (void)in_sizes; (void)n_in; (void)d_ws; (void)ws_size; (void)out_size;
    const float* x  = (const float*)d_in[0];
    const float* W1 = (const float*)d_in[1];
    const float* b1 = (const float*)d_in[2];
    const float* W2 = (const float*)d_in[3];
    const float* b2 = (const float*)d_in[4];
    float* out = (float*)d_out;
    poatt_kernel<<<dim3(NPOS), dim3(256), 0, stream>>>(x, W1, b1, W2, b2, out);
}

// Round 2
// 158.730 us; speedup vs baseline: 2.0483x; 2.0483x over previous
//
#include <hip/hip_runtime.h>

#define CH   128
#define KS   7
#define R    49          // KS*KS
#define HH   56
#define NPOS 3136        // HH*HH
#define BS   8
#define XSTR 401408      // CH*NPOS (one batch plane of x)
#define XTOT (BS*XSTR)

// One block per pos. 256 threads = 128 ch x 2 halves (g).
// Phase 2: g = m-half (each thread computes partial P over 64 of 128 m).
// Phase 4: g = batch-half (each thread owns full 49-rr column for 4 batches).
template<bool USE_WS>
__global__ __launch_bounds__(256, 4) void poatt_main(
    const float* __restrict__ x,
    const float* __restrict__ W1, const float* __restrict__ b1,
    const float* __restrict__ W2, const float* __restrict__ b2,
    float* __restrict__ dst)   // USE_WS: (b,pos,ch) scratch ; else (b,ch,pos) out
{
    __shared__ float rel_s[R][2];
    __shared__ float buf[R * CH];   // overlay: hid -> P-partial exchange -> weights

    const int pos = blockIdx.x;
    const int tid = threadIdx.x;
    const int ch  = tid & (CH - 1);
    const int g   = tid >> 7;

    const int q  = pos >> 6;        // block-uniform window id
    const int ii = q / KS;
    const int jj = q % KS;

    // ---------- phase 0: rel[rr][e] (coords nbhd extract, d=2) ----------
    if (tid < 2 * R) {
        const int e  = (tid >= R) ? 1 : 0;
        const int rr = tid - e * R;
        int F  = (pos * 2 + e) * R + rr;
        int ep = F & 1;
        int t  = F >> 1;
        int jp = t % HH; t /= HH;
        int a  = t % HH; t /= HH;
        int jc = t % KS;
        int ic = t / KS;
        int row = jp + ic - 3;
        int col = ep + jc - 3;
        float v = 0.0f;
        if (row >= 0 && row < HH && (col == 0 || col == 1)) {
            int f    = a * (HH * 2) + row * 2 + col;
            int cidx = f / NPOS;
            int p    = f - cidx * NPOS;
            int u    = (cidx == 0) ? (p / HH) : (p % HH);
            v = -3.0f + 6.0f * (float)u * (1.0f / 55.0f);
        }
        const float c0 = -3.0f + 6.0f * (float)(pos / HH) * (1.0f / 55.0f);
        const float c1 = -3.0f + 6.0f * (float)(pos % HH) * (1.0f / 55.0f);
        rel_s[rr][e] = v - ((e == 0) ? c0 : c1);
    }
    __syncthreads();

    // ---------- phase 1: hid = relu(rel @ W1 + b1), layout buf[rr*CH + m] ----------
    {
        const float w10 = W1[ch];
        const float w11 = W1[CH + ch];
        const float bb  = b1[ch];
        for (int rr = g; rr < R; rr += 2) {
            float h = fmaf(rel_s[rr][0], w10, fmaf(rel_s[rr][1], w11, bb));
            buf[rr * CH + ch] = fmaxf(h, 0.0f);
        }
    }
    __syncthreads();

    // ---------- phase 2: partial P[rr] over m in [64g, 64g+64) ----------
    float p[R];
    #pragma unroll
    for (int i = 0; i < R; ++i) p[i] = 0.0f;
    {
        const int m0 = g * 64;
        for (int m4 = 0; m4 < 16; ++m4) {
            const int m = m0 + m4 * 4;
            float4 w;
            w.x = W2[(m + 0) * CH + ch];
            w.y = W2[(m + 1) * CH + ch];
            w.z = W2[(m + 2) * CH + ch];
            w.w = W2[(m + 3) * CH + ch];
            #pragma unroll
            for (int rr = 0; rr < R; ++rr) {
                const float4 h = *reinterpret_cast<const float4*>(&buf[rr * CH + m]);
                p[rr] = fmaf(h.x, w.x, fmaf(h.y, w.y, fmaf(h.z, w.z, fmaf(h.w, w.w, p[rr]))));
            }
        }
    }
    __syncthreads();                 // all hid reads done; buf reusable

    // ---------- phase 3: exchange partials, softmax + validity mask (g==0) ----------
    if (g == 1) {
        #pragma unroll
        for (int rr = 0; rr < R; ++rr) buf[rr * CH + ch] = p[rr];
    }
    __syncthreads();
    if (g == 0) {
        const float bb = b2[ch];
        #pragma unroll
        for (int rr = 0; rr < R; ++rr) p[rr] += buf[rr * CH + ch] + bb;
        float mx = p[0];
        #pragma unroll
        for (int rr = 1; rr < R; ++rr) mx = fmaxf(mx, p[rr]);
        float s = 0.0f;
        #pragma unroll
        for (int rr = 0; rr < R; ++rr) { p[rr] = __expf(p[rr] - mx); s += p[rr]; }
        const float inv = 1.0f / s;
        const int wb0 = (pos & 63) * (R * CH);
        #pragma unroll
        for (int rr = 0; rr < R; ++rr) {
            int rem = wb0 + ch * R + rr;
            int e2  = rem & (CH - 1);
            int j2  = (rem >> 7) % HH;
            int row = j2 + ii - 3;
            int col = e2 + jj - 3;
            bool valid = (row >= 0) && (row < HH) && (col >= 0) && (col < CH);
            p[rr] = valid ? p[rr] * inv : 0.0f;
            buf[rr * CH + ch] = p[rr];
        }
    }
    __syncthreads();
    if (g == 1) {
        #pragma unroll
        for (int rr = 0; rr < R; ++rr) p[rr] = buf[rr * CH + ch];
    }

    // ---------- phase 4: direct-global gather, 4 batches per thread, no syncs ----------
    const int winbase = (pos & 63) * (R * CH) + (ii - 3) * CH + (jj - 3);
    const int base_t  = winbase + ch * R;

    #pragma unroll
    for (int bi = 0; bi < 4; ++bi) {
        const int b  = g * 4 + bi;
        const int ab = b * XSTR + base_t;
        // block-uniform in-bounds check (scalar branch): OOB only b==0 low / b==7 high
        const bool safe = (b > 0 || winbase >= 0) && (b < BS - 1 || winbase + R * CH <= XSTR);
        float acc = 0.0f;
        if (safe) {
            #pragma unroll
            for (int rr = 0; rr < R; ++rr) acc = fmaf(p[rr], x[ab + rr], acc);
        } else {
            #pragma unroll
            for (int rr = 0; rr < R; ++rr) {
                int a2 = ab + rr;
                a2 = a2 < 0 ? 0 : (a2 >= XTOT ? XTOT - 1 : a2);   // masked (weight 0) anyway
                acc = fmaf(p[rr], x[a2], acc);
            }
        }
        if (USE_WS) dst[((size_t)b * NPOS + pos) * CH + ch] = acc;
        else        dst[((size_t)b * CH + ch) * NPOS + pos] = acc;
    }
}

// transpose (b,pos,ch) -> (b,ch,pos), LDS-tiled 64 pos x 128 ch
__global__ __launch_bounds__(256) void poatt_tr(
    const float* __restrict__ ws, float* __restrict__ out)
{
    __shared__ float t[64 * 129];
    const int blk = blockIdx.x;          // 8 * 49
    const int b   = blk / 49;
    const int p0  = (blk % 49) * 64;
    const int tid = threadIdx.x;

    const int chR = tid & 127, pR = tid >> 7;
    #pragma unroll
    for (int r = 0; r < 32; ++r) {
        int pl = pR + 2 * r;
        t[pl * 129 + chR] = ws[((size_t)b * NPOS + p0 + pl) * CH + chR];
    }
    __syncthreads();
    const int pW = tid & 63, chW0 = tid >> 6;
    #pragma unroll
    for (int c = 0; c < 32; ++c) {
        int chl = chW0 + 4 * c;
        out[((size_t)b * CH + chl) * NPOS + p0 + pW] = t[pW * 129 + chl];
    }
}

extern "C" void kernel_launch(void* const* d_in, const int* in_sizes, int n_in,
                              void* d_out, int out_size, void* d_ws, size_t ws_size,
                              hipStream_t stream) {
    (void)in_sizes; (void)n_in; (void)out_size;
    const float* x  = (const float*)d_in[0];
    const float* W1 = (const float*)d_in[1];
    const float* b1 = (const float*)d_in[2];
    const float* W2 = (const float*)d_in[3];
    const float* b2 = (const float*)d_in[4];
    float* out = (float*)d_out;

    const size_t need = (size_t)BS * NPOS * CH * sizeof(float);
    if (ws_size >= need) {
        float* ws = (float*)d_ws;
        poatt_main<true><<<dim3(NPOS), dim3(256), 0, stream>>>(x, W1, b1, W2, b2, ws);
        poatt_tr<<<dim3(BS * 49), dim3(256), 0, stream>>>(ws, out);
    } else {
        poatt_main<false><<<dim3(NPOS), dim3(256), 0, stream>>>(x, W1, b1, W2, b2, out);
    }
}